// Round 3
// baseline (330.955 us; speedup 1.0000x reference)
//
#include <hip/hip_runtime.h>

#define I_LEN 1024
#define S_LEN 4096

typedef float f32x4 __attribute__((ext_vector_type(4)));

__device__ __forceinline__ unsigned int f2h(float f) {
  _Float16 h = (_Float16)f; unsigned short u;
  __builtin_memcpy(&u, &h, 2); return (unsigned int)u;
}
__device__ __forceinline__ float h2f(unsigned int u) {
  unsigned short s = (unsigned short)u; _Float16 h;
  __builtin_memcpy(&h, &s, 2); return (float)h;
}

// ---------------------------------------------------------------------------
// K1a: single pass over m. Block = 64 cols x 32 s-rows (256 thr, 4 waves).
// Wave = 16 cols x 4 s-subgroups (sg = lane>>4), 8 s-rows per thread.
// All loads/stores wave-contiguous; q-partials reduced IN-WAVE (shfl) ->
// one partial per column per 32-row block. No LDS, no barriers.
// Emits: kvS[s][i] (fp16 k,v packed; 0xFFFFFFFF sentinel = masked-out),
//        glS[s][i][8] u16 fixed-point gate values,
//        qpart[sb][i][12] f32 partials.
// ---------------------------------------------------------------------------
__global__ __launch_bounds__(256, 2) void msa_k1a(
    const float* __restrict__ m, const float* __restrict__ mask,
    const float* __restrict__ lng, const float* __restrict__ lnb,
    const float* __restrict__ Wk, const float* __restrict__ Wv,
    const float* __restrict__ Wg, const float* __restrict__ bg,
    unsigned int* __restrict__ kvS, uint4* __restrict__ glS,
    float* __restrict__ qpart)
{
  const int b  = blockIdx.x;        // 2048 = 16 col-groups x 128 s-blocks
  const int cg = b & 15;
  const int sb = b >> 4;
  const int t  = threadIdx.x;
  const int w  = t >> 6;
  const int l  = t & 63;
  const int i  = cg * 64 + w * 16 + (l & 15);
  const int sg = l >> 4;
  const int s0 = sb * 32 + sg * 8;

  // uniform folded weights (SGPR-sourced)
  float swk = 0.f, swv = 0.f, kb = 0.f, vb = 0.f;
  float sgv[8], tbv[8];
#pragma unroll
  for (int c = 0; c < 8; ++c) {
    swk = fmaf(lng[c], Wk[c], swk);  swv = fmaf(lng[c], Wv[c], swv);
    kb  = fmaf(lnb[c], Wk[c], kb);   vb  = fmaf(lnb[c], Wv[c], vb);
  }
#pragma unroll
  for (int h = 0; h < 8; ++h) {
    float sv_ = 0.f, tb = bg[h];
#pragma unroll
    for (int c = 0; c < 8; ++c) {
      sv_ = fmaf(lng[c], Wg[c * 8 + h], sv_);
      tb  = fmaf(lnb[c], Wg[c * 8 + h], tb);
    }
    sgv[h] = sv_; tbv[h] = tb;
  }

  float qnx[8] = {0,0,0,0,0,0,0,0};
  float qd = 0.f;

#pragma unroll
  for (int half = 0; half < 2; ++half) {
    // 12-deep load issue before any use: 4x(float4,float4) + 4 mask dwords
    float4 L[4], H[4]; float MK[4];
#pragma unroll
    for (int r = 0; r < 4; ++r) {
      const int s = s0 + half * 4 + r;
      const size_t base = (size_t)(s * I_LEN + i);
      const float4* mp = (const float4*)(m + base * 8);
      L[r] = mp[0]; H[r] = mp[1];
      MK[r] = mask[base];
    }
#pragma unroll
    for (int r = 0; r < 4; ++r) {
      const int s = s0 + half * 4 + r;
      const size_t base = (size_t)(s * I_LEN + i);
      float x[8] = {L[r].x, L[r].y, L[r].z, L[r].w, H[r].x, H[r].y, H[r].z, H[r].w};
      const float mk = MK[r];
      float su = 0.f, s2 = 0.f;
#pragma unroll
      for (int c = 0; c < 8; ++c) { su += x[c]; s2 = fmaf(x[c], x[c], s2); }
      const float mu   = su * 0.125f;
      const float var  = s2 * 0.125f - mu * mu;
      const float rstd = rsqrtf(var + 1e-5f);
      float dk = 0.f, dv = 0.f;
#pragma unroll
      for (int c = 0; c < 8; ++c) {
        const float xg = x[c] * lng[c];          // gamma fold
        dk = fmaf(xg, Wk[c], dk);
        dv = fmaf(xg, Wv[c], dv);
        x[c] = xg;
      }
      const float kk = fmaf(rstd, fmaf(-mu, swk, dk), kb);
      const float vv = fmaf(rstd, fmaf(-mu, swv, dv), vb);

      // gate logits -> sigmoid -> u16 fixed point, packed 8x
      unsigned int gw[4];
#pragma unroll
      for (int j = 0; j < 4; ++j) {
        float d0 = 0.f, d1 = 0.f;
#pragma unroll
        for (int c = 0; c < 8; ++c) {
          d0 = fmaf(x[c], Wg[c * 8 + 2 * j],     d0);
          d1 = fmaf(x[c], Wg[c * 8 + 2 * j + 1], d1);
        }
        const float gl0 = fmaf(rstd, fmaf(-mu, sgv[2 * j],     d0), tbv[2 * j]);
        const float gl1 = fmaf(rstd, fmaf(-mu, sgv[2 * j + 1], d1), tbv[2 * j + 1]);
        const float g0 = 65535.f / (1.0f + __expf(-gl0));
        const float g1 = 65535.f / (1.0f + __expf(-gl1));
        const unsigned int u0 = (unsigned int)__float2int_rn(g0);
        const unsigned int u1 = (unsigned int)__float2int_rn(g1);
        gw[j] = u0 | (u1 << 16);
      }
      glS[base] = make_uint4(gw[0], gw[1], gw[2], gw[3]);
      kvS[base] = (mk > 0.5f) ? ((f2h(kk) << 16) | f2h(vv)) : 0xFFFFFFFFu;

      const float mr  = mk * rstd;
      const float mmr = -mu * mr;
#pragma unroll
      for (int c = 0; c < 8; ++c)
        qnx[c] = fmaf(x[c], mr, fmaf(lng[c], mmr, qnx[c]));
      qd += mk;
    }
  }

  // in-wave reduce over sg (lanes l, l^16, l^32, l^48 share column i)
  float red[9];
#pragma unroll
  for (int q = 0; q < 9; ++q) {
    float x = (q < 8) ? qnx[q] : qd;
    x += __shfl_xor(x, 16);
    x += __shfl_xor(x, 32);
    red[q] = x;
  }
  if (l < 16) {
    float4* pp = (float4*)(qpart + ((size_t)sb * I_LEN + i) * 12);
    pp[0] = make_float4(red[0], red[1], red[2], red[3]);
    pp[1] = make_float4(red[4], red[5], red[6], red[7]);
    pp[2] = make_float4(red[8], 0.f, 0.f, 0.f);
  }
}

// ---------------------------------------------------------------------------
// K1b: reduce qpart (128 partials/column) -> pooled q -> qtab[i][8].
// 256 blocks x 64 threads (1 wave): wave = 4 columns x 16 slices.
// ---------------------------------------------------------------------------
__global__ __launch_bounds__(64) void msa_k1b(
    const float* __restrict__ lnb, const float* __restrict__ Wq,
    const float* __restrict__ qpart, float* __restrict__ qtab)
{
  const int l  = threadIdx.x;
  const int i  = blockIdx.x * 4 + (l & 3);
  const int sl = l >> 2;             // 16 slices
  float acc[9] = {0,0,0,0,0,0,0,0,0};
#pragma unroll
  for (int it = 0; it < 8; ++it) {
    const int sb = sl + it * 16;
    const float4* p = (const float4*)(qpart + ((size_t)sb * I_LEN + i) * 12);
    const float4 a = p[0], b4 = p[1], c4 = p[2];
    acc[0] += a.x;  acc[1] += a.y;  acc[2] += a.z;  acc[3] += a.w;
    acc[4] += b4.x; acc[5] += b4.y; acc[6] += b4.z; acc[7] += b4.w;
    acc[8] += c4.x;
  }
#pragma unroll
  for (int q = 0; q < 9; ++q) {
    float x = acc[q];
    x += __shfl_xor(x, 4);
    x += __shfl_xor(x, 8);
    x += __shfl_xor(x, 16);
    x += __shfl_xor(x, 32);
    acc[q] = x;
  }
  if (l < 4) {
    const float d   = acc[8];
    const float inv = 1.0f / (d + 1e-5f);
    float qs[8];
#pragma unroll
    for (int c = 0; c < 8; ++c) qs[c] = (acc[c] + lnb[c] * d) * inv;
    float qv[8];
#pragma unroll
    for (int h = 0; h < 8; ++h) {
      float v = 0.f;
#pragma unroll
      for (int c = 0; c < 8; ++c) v = fmaf(qs[c], Wq[c * 8 + h], v);
      qv[h] = v;                      // c_h^-0.5 == 1
    }
    float4* qp = (float4*)(qtab + (size_t)i * 8);
    qp[0] = make_float4(qv[0], qv[1], qv[2], qv[3]);
    qp[1] = make_float4(qv[4], qv[5], qv[6], qv[7]);
  }
}

// ---------------------------------------------------------------------------
// K1c: softmax partial sums over kvS. Same decomposition as K1a.
// Writes spart[sb][i][16] = {se[8], sv[8]}.
// ---------------------------------------------------------------------------
__global__ __launch_bounds__(256, 2) void msa_k1c(
    const unsigned int* __restrict__ kvS, const float* __restrict__ qtab,
    float* __restrict__ spart)
{
  const int b  = blockIdx.x;
  const int cg = b & 15;
  const int sb = b >> 4;
  const int t  = threadIdx.x;
  const int w  = t >> 6;
  const int l  = t & 63;
  const int i  = cg * 64 + w * 16 + (l & 15);
  const int sg = l >> 4;
  const int s0 = sb * 32 + sg * 8;

  const float4* qp = (const float4*)(qtab + (size_t)i * 8);
  const float4 q0 = qp[0], q1 = qp[1];
  const float qh[8] = {q0.x, q0.y, q0.z, q0.w, q1.x, q1.y, q1.z, q1.w};

  float se[8] = {0,0,0,0,0,0,0,0};
  float sv[8] = {0,0,0,0,0,0,0,0};
#pragma unroll
  for (int half = 0; half < 2; ++half) {
    unsigned int W[4];
#pragma unroll
    for (int r = 0; r < 4; ++r)
      W[r] = kvS[(size_t)((s0 + half * 4 + r) * I_LEN + i)];
#pragma unroll
    for (int r = 0; r < 4; ++r) {
      const unsigned int wv = W[r];
      const bool on = (wv != 0xFFFFFFFFu);
      const float kk = h2f(wv >> 16);
      const float vv = h2f(wv & 0xFFFFu);
#pragma unroll
      for (int h = 0; h < 8; ++h) {
        const float e = on ? __expf(qh[h] * kk) : 0.0f;
        se[h] += e;
        sv[h] = fmaf(e, vv, sv[h]);
      }
    }
  }
  float red[16];
#pragma unroll
  for (int q = 0; q < 16; ++q) {
    float x = (q < 8) ? se[q] : sv[q - 8];
    x += __shfl_xor(x, 16);
    x += __shfl_xor(x, 32);
    red[q] = x;
  }
  if (l < 16) {
    float4* pp = (float4*)(spart + ((size_t)sb * I_LEN + i) * 16);
    pp[0] = make_float4(red[0],  red[1],  red[2],  red[3]);
    pp[1] = make_float4(red[4],  red[5],  red[6],  red[7]);
    pp[2] = make_float4(red[8],  red[9],  red[10], red[11]);
    pp[3] = make_float4(red[12], red[13], red[14], red[15]);
  }
}

// ---------------------------------------------------------------------------
// K1d: reduce spart -> o_tab[i][8] = sum(e*v)/sum(e).
// ---------------------------------------------------------------------------
__global__ __launch_bounds__(64) void msa_k1d(
    const float* __restrict__ spart, float* __restrict__ o_tab)
{
  const int l  = threadIdx.x;
  const int i  = blockIdx.x * 4 + (l & 3);
  const int sl = l >> 2;
  float acc[16] = {0,0,0,0,0,0,0,0,0,0,0,0,0,0,0,0};
#pragma unroll
  for (int it = 0; it < 8; ++it) {
    const int sb = sl + it * 16;
    const float4* p = (const float4*)(spart + ((size_t)sb * I_LEN + i) * 16);
    const float4 a = p[0], b4 = p[1], c4 = p[2], d4 = p[3];
    acc[0]  += a.x;  acc[1]  += a.y;  acc[2]  += a.z;  acc[3]  += a.w;
    acc[4]  += b4.x; acc[5]  += b4.y; acc[6]  += b4.z; acc[7]  += b4.w;
    acc[8]  += c4.x; acc[9]  += c4.y; acc[10] += c4.z; acc[11] += c4.w;
    acc[12] += d4.x; acc[13] += d4.y; acc[14] += d4.z; acc[15] += d4.w;
  }
#pragma unroll
  for (int q = 0; q < 16; ++q) {
    float x = acc[q];
    x += __shfl_xor(x, 4);
    x += __shfl_xor(x, 8);
    x += __shfl_xor(x, 16);
    x += __shfl_xor(x, 32);
    acc[q] = x;
  }
  if (l < 4) {
    float4* op = (float4*)(o_tab + (size_t)i * 8);
    op[0] = make_float4(acc[8]  / acc[0], acc[9]  / acc[1],
                        acc[10] / acc[2], acc[11] / acc[3]);
    op[1] = make_float4(acc[12] / acc[4], acc[13] / acc[5],
                        acc[14] / acc[6], acc[15] / acc[7]);
  }
}

// ---------------------------------------------------------------------------
// K2: gate * attention -> output. Reads glS (16 B/point) instead of m
// (32 B/point) -- m is read exactly once in the whole pipeline (K1a).
// Non-temporal out stores (never re-read).
// ---------------------------------------------------------------------------
__global__ __launch_bounds__(256, 2) void msa_k2(
    const uint4* __restrict__ glS, const float* __restrict__ o_tab,
    const float* __restrict__ Wo, const float* __restrict__ bo,
    float* __restrict__ out)
{
  const int tid = blockIdx.x * 256 + threadIdx.x;   // 524288 threads
  const int i = tid & (I_LEN - 1);

  const float4* op = (const float4*)(o_tab + (size_t)i * 8);
  const float4 o1 = op[0], o2 = op[1];
  const float kfx = 1.0f / 65535.f;
  const float A[8] = {o1.x * kfx, o1.y * kfx, o1.z * kfx, o1.w * kfx,
                      o2.x * kfx, o2.y * kfx, o2.z * kfx, o2.w * kfx};

#pragma unroll 2
  for (int q = 0; q < 8; ++q) {
    const size_t p = (size_t)tid + (size_t)q * 524288;
    const uint4 G = glS[p];
    const unsigned int gw[4] = {G.x, G.y, G.z, G.w};
    float acc[8];
#pragma unroll
    for (int c = 0; c < 8; ++c) acc[c] = bo[c];
#pragma unroll
    for (int j = 0; j < 4; ++j) {
      const float gv0 = A[2 * j]     * (float)(gw[j] & 0xFFFFu);
      const float gv1 = A[2 * j + 1] * (float)(gw[j] >> 16);
#pragma unroll
      for (int c = 0; c < 8; ++c) {
        acc[c] = fmaf(gv0, Wo[(2 * j) * 8 + c], acc[c]);
        acc[c] = fmaf(gv1, Wo[(2 * j + 1) * 8 + c], acc[c]);
      }
    }
    f32x4* outp = (f32x4*)(out + p * 8);
    f32x4 r0 = {acc[0], acc[1], acc[2], acc[3]};
    f32x4 r1 = {acc[4], acc[5], acc[6], acc[7]};
    __builtin_nontemporal_store(r0, outp);
    __builtin_nontemporal_store(r1, outp + 1);
  }
}

extern "C" void kernel_launch(void* const* d_in, const int* in_sizes, int n_in,
                              void* d_out, int out_size, void* d_ws, size_t ws_size,
                              hipStream_t stream) {
  const float* m    = (const float*)d_in[0];
  const float* mask = (const float*)d_in[1];
  const float* lng  = (const float*)d_in[2];
  const float* lnb  = (const float*)d_in[3];
  const float* Wq   = (const float*)d_in[4];
  const float* Wk   = (const float*)d_in[5];
  const float* Wv   = (const float*)d_in[6];
  const float* Wg   = (const float*)d_in[7];
  const float* bg   = (const float*)d_in[8];
  const float* Wo   = (const float*)d_in[9];
  const float* bo   = (const float*)d_in[10];
  float* out = (float*)d_out;

  // ws layout (all within 128 MiB):
  //   o_tab 32KB @0 | qtab 32KB @64K | kvS 16.8MB @1M | glS 67.1MB @32M |
  //   qpart 6.3MB @104M | spart 8.4MB @112M
  char* ws = (char*)d_ws;
  float*        o_tab = (float*)ws;
  float*        qtab  = (float*)(ws + ((size_t)64 << 10));
  unsigned int* kvS   = (unsigned int*)(ws + ((size_t)1 << 20));
  uint4*        glS   = (uint4*)(ws + ((size_t)32 << 20));
  float*        qpart = (float*)(ws + ((size_t)104 << 20));
  float*        spart = (float*)(ws + ((size_t)112 << 20));

  hipLaunchKernelGGL(msa_k1a, dim3(2048), dim3(256), 0, stream,
                     m, mask, lng, lnb, Wk, Wv, Wg, bg, kvS, glS, qpart);
  hipLaunchKernelGGL(msa_k1b, dim3(256), dim3(64), 0, stream,
                     lnb, Wq, qpart, qtab);
  hipLaunchKernelGGL(msa_k1c, dim3(2048), dim3(256), 0, stream,
                     kvS, qtab, spart);
  hipLaunchKernelGGL(msa_k1d, dim3(256), dim3(64), 0, stream,
                     spart, o_tab);
  hipLaunchKernelGGL(msa_k2, dim3(2048), dim3(256), 0, stream,
                     glS, o_tab, Wo, bo, out);
}

// Round 4
// 328.843 us; speedup vs baseline: 1.0064x; 1.0064x over previous
//
#include <hip/hip_runtime.h>

#define I_LEN 1024
#define S_LEN 4096

typedef float f32x4 __attribute__((ext_vector_type(4)));

__device__ __forceinline__ unsigned int f2h(float f) {
  _Float16 h = (_Float16)f; unsigned short u;
  __builtin_memcpy(&u, &h, 2); return (unsigned int)u;
}
__device__ __forceinline__ float h2f(unsigned int u) {
  unsigned short s = (unsigned short)u; _Float16 h;
  __builtin_memcpy(&h, &s, 2); return (float)h;
}

// ---------------------------------------------------------------------------
// K1a (lean): single pass over m. Block = 64 cols x 32 s-rows (256 thr).
// Wave = 16 cols x 4 s-subgroups; 8 s-rows/thread. ALL 24 loads issued into
// named registers BEFORE any compute (sched_barrier pins the boundary) ->
// ~9 KB in flight per wave instead of the ~0.25 KB the compiler was leaving
// us with (VGPR=28/64 in R2/R3 -> 1.5 TB/s latency wall).
// Emits kvS[s][i] (fp16 k,v packed; 0xFFFFFFFF = masked-out) + qpart.
// ---------------------------------------------------------------------------
__global__ __launch_bounds__(256, 2) void msa_k1a(
    const float* __restrict__ m, const float* __restrict__ mask,
    const float* __restrict__ lng, const float* __restrict__ lnb,
    const float* __restrict__ Wk, const float* __restrict__ Wv,
    unsigned int* __restrict__ kvS, float* __restrict__ qpart)
{
  const int b  = blockIdx.x;        // 2048 = 16 col-groups x 128 s-blocks
  const int cg = b & 15;
  const int sb = b >> 4;
  const int t  = threadIdx.x;
  const int w  = t >> 6;
  const int l  = t & 63;
  const int i  = cg * 64 + w * 16 + (l & 15);
  const int sg = l >> 4;
  const int s0 = sb * 32 + sg * 8;

  // uniform folded weights (SGPR-sourced)
  float swk = 0.f, swv = 0.f, kb = 0.f, vb = 0.f;
#pragma unroll
  for (int c = 0; c < 8; ++c) {
    swk = fmaf(lng[c], Wk[c], swk);  swv = fmaf(lng[c], Wv[c], swv);
    kb  = fmaf(lnb[c], Wk[c], kb);   vb  = fmaf(lnb[c], Wv[c], vb);
  }

  // ---- forced load batch: 8 rows x (2 float4 + 1 float) = 24 loads ----
  float4 L[8], H[8]; float MK[8];
#pragma unroll
  for (int r = 0; r < 8; ++r) {
    const size_t base = (size_t)((s0 + r) * I_LEN + i);
    const float4* mp = (const float4*)(m + base * 8);
    L[r] = mp[0]; H[r] = mp[1];
    MK[r] = mask[base];
  }
  __builtin_amdgcn_sched_barrier(0);   // nothing crosses: loads stay above

  float qnx[8] = {0,0,0,0,0,0,0,0};
  float qd = 0.f;
#pragma unroll
  for (int r = 0; r < 8; ++r) {
    const size_t base = (size_t)((s0 + r) * I_LEN + i);
    float x[8] = {L[r].x, L[r].y, L[r].z, L[r].w, H[r].x, H[r].y, H[r].z, H[r].w};
    const float mk = MK[r];
    float su = 0.f, s2 = 0.f;
#pragma unroll
    for (int c = 0; c < 8; ++c) { su += x[c]; s2 = fmaf(x[c], x[c], s2); }
    const float mu   = su * 0.125f;
    const float var  = s2 * 0.125f - mu * mu;
    const float rstd = rsqrtf(var + 1e-5f);
    float dk = 0.f, dv = 0.f;
#pragma unroll
    for (int c = 0; c < 8; ++c) {
      const float xg = x[c] * lng[c];          // gamma fold
      dk = fmaf(xg, Wk[c], dk);
      dv = fmaf(xg, Wv[c], dv);
      x[c] = xg;
    }
    const float kk = fmaf(rstd, fmaf(-mu, swk, dk), kb);
    const float vv = fmaf(rstd, fmaf(-mu, swv, dv), vb);
    kvS[base] = (mk > 0.5f) ? ((f2h(kk) << 16) | f2h(vv)) : 0xFFFFFFFFu;

    const float mr  = mk * rstd;
    const float mmr = -mu * mr;
#pragma unroll
    for (int c = 0; c < 8; ++c)
      qnx[c] = fmaf(x[c], mr, fmaf(lng[c], mmr, qnx[c]));
    qd += mk;
  }

  // in-wave reduce over sg (lanes l, l^16, l^32, l^48 share column i)
  float red[9];
#pragma unroll
  for (int q = 0; q < 9; ++q) {
    float x = (q < 8) ? qnx[q] : qd;
    x += __shfl_xor(x, 16);
    x += __shfl_xor(x, 32);
    red[q] = x;
  }
  if (l < 16) {
    float4* pp = (float4*)(qpart + ((size_t)sb * I_LEN + i) * 12);
    pp[0] = make_float4(red[0], red[1], red[2], red[3]);
    pp[1] = make_float4(red[4], red[5], red[6], red[7]);
    pp[2] = make_float4(red[8], 0.f, 0.f, 0.f);
  }
}

// ---------------------------------------------------------------------------
// K1b: reduce qpart (128 partials/column) -> pooled q -> qtab[i][8].
// ---------------------------------------------------------------------------
__global__ __launch_bounds__(64) void msa_k1b(
    const float* __restrict__ lnb, const float* __restrict__ Wq,
    const float* __restrict__ qpart, float* __restrict__ qtab)
{
  const int l  = threadIdx.x;
  const int i  = blockIdx.x * 4 + (l & 3);
  const int sl = l >> 2;             // 16 slices
  float acc[9] = {0,0,0,0,0,0,0,0,0};
#pragma unroll
  for (int it = 0; it < 8; ++it) {
    const int sb = sl + it * 16;
    const float4* p = (const float4*)(qpart + ((size_t)sb * I_LEN + i) * 12);
    const float4 a = p[0], b4 = p[1], c4 = p[2];
    acc[0] += a.x;  acc[1] += a.y;  acc[2] += a.z;  acc[3] += a.w;
    acc[4] += b4.x; acc[5] += b4.y; acc[6] += b4.z; acc[7] += b4.w;
    acc[8] += c4.x;
  }
#pragma unroll
  for (int q = 0; q < 9; ++q) {
    float x = acc[q];
    x += __shfl_xor(x, 4);
    x += __shfl_xor(x, 8);
    x += __shfl_xor(x, 16);
    x += __shfl_xor(x, 32);
    acc[q] = x;
  }
  if (l < 4) {
    const float d   = acc[8];
    const float inv = 1.0f / (d + 1e-5f);
    float qs[8];
#pragma unroll
    for (int c = 0; c < 8; ++c) qs[c] = (acc[c] + lnb[c] * d) * inv;
    float qv[8];
#pragma unroll
    for (int h = 0; h < 8; ++h) {
      float v = 0.f;
#pragma unroll
      for (int c = 0; c < 8; ++c) v = fmaf(qs[c], Wq[c * 8 + h], v);
      qv[h] = v;                      // c_h^-0.5 == 1
    }
    float4* qp = (float4*)(qtab + (size_t)i * 8);
    qp[0] = make_float4(qv[0], qv[1], qv[2], qv[3]);
    qp[1] = make_float4(qv[4], qv[5], qv[6], qv[7]);
  }
}

// ---------------------------------------------------------------------------
// K1c: softmax partial sums over kvS (batched loads). -> spart[sb][i][16]
// ---------------------------------------------------------------------------
__global__ __launch_bounds__(256, 2) void msa_k1c(
    const unsigned int* __restrict__ kvS, const float* __restrict__ qtab,
    float* __restrict__ spart)
{
  const int b  = blockIdx.x;
  const int cg = b & 15;
  const int sb = b >> 4;
  const int t  = threadIdx.x;
  const int w  = t >> 6;
  const int l  = t & 63;
  const int i  = cg * 64 + w * 16 + (l & 15);
  const int sg = l >> 4;
  const int s0 = sb * 32 + sg * 8;

  const float4* qp = (const float4*)(qtab + (size_t)i * 8);
  const float4 q0 = qp[0], q1 = qp[1];
  const float qh[8] = {q0.x, q0.y, q0.z, q0.w, q1.x, q1.y, q1.z, q1.w};

  unsigned int W[8];
#pragma unroll
  for (int r = 0; r < 8; ++r)
    W[r] = kvS[(size_t)((s0 + r) * I_LEN + i)];
  __builtin_amdgcn_sched_barrier(0);

  float se[8] = {0,0,0,0,0,0,0,0};
  float sv[8] = {0,0,0,0,0,0,0,0};
#pragma unroll
  for (int r = 0; r < 8; ++r) {
    const unsigned int wv = W[r];
    const bool on = (wv != 0xFFFFFFFFu);
    const float kk = h2f(wv >> 16);
    const float vv = on ? h2f(wv & 0xFFFFu) : 0.0f;
#pragma unroll
    for (int h = 0; h < 8; ++h) {
      const float e = on ? __expf(qh[h] * kk) : 0.0f;
      se[h] += e;
      sv[h] = fmaf(e, vv, sv[h]);
    }
  }
  float red[16];
#pragma unroll
  for (int q = 0; q < 16; ++q) {
    float x = (q < 8) ? se[q] : sv[q - 8];
    x += __shfl_xor(x, 16);
    x += __shfl_xor(x, 32);
    red[q] = x;
  }
  if (l < 16) {
    float4* pp = (float4*)(spart + ((size_t)sb * I_LEN + i) * 16);
    pp[0] = make_float4(red[0],  red[1],  red[2],  red[3]);
    pp[1] = make_float4(red[4],  red[5],  red[6],  red[7]);
    pp[2] = make_float4(red[8],  red[9],  red[10], red[11]);
    pp[3] = make_float4(red[12], red[13], red[14], red[15]);
  }
}

// ---------------------------------------------------------------------------
// K1d: reduce spart -> o_tab[i][8] = sum(e*v)/sum(e).
// ---------------------------------------------------------------------------
__global__ __launch_bounds__(64) void msa_k1d(
    const float* __restrict__ spart, float* __restrict__ o_tab)
{
  const int l  = threadIdx.x;
  const int i  = blockIdx.x * 4 + (l & 3);
  const int sl = l >> 2;
  float acc[16] = {0,0,0,0,0,0,0,0,0,0,0,0,0,0,0,0};
#pragma unroll
  for (int it = 0; it < 8; ++it) {
    const int sb = sl + it * 16;
    const float4* p = (const float4*)(spart + ((size_t)sb * I_LEN + i) * 16);
    const float4 a = p[0], b4 = p[1], c4 = p[2], d4 = p[3];
    acc[0]  += a.x;  acc[1]  += a.y;  acc[2]  += a.z;  acc[3]  += a.w;
    acc[4]  += b4.x; acc[5]  += b4.y; acc[6]  += b4.z; acc[7]  += b4.w;
    acc[8]  += c4.x; acc[9]  += c4.y; acc[10] += c4.z; acc[11] += c4.w;
    acc[12] += d4.x; acc[13] += d4.y; acc[14] += d4.z; acc[15] += d4.w;
  }
#pragma unroll
  for (int q = 0; q < 16; ++q) {
    float x = acc[q];
    x += __shfl_xor(x, 4);
    x += __shfl_xor(x, 8);
    x += __shfl_xor(x, 16);
    x += __shfl_xor(x, 32);
    acc[q] = x;
  }
  if (l < 4) {
    float4* op = (float4*)(o_tab + (size_t)i * 8);
    op[0] = make_float4(acc[8]  / acc[0], acc[9]  / acc[1],
                        acc[10] / acc[2], acc[11] / acc[3]);
    op[1] = make_float4(acc[12] / acc[4], acc[13] / acc[5],
                        acc[14] / acc[6], acc[15] / acc[7]);
  }
}

// ---------------------------------------------------------------------------
// K2: re-read m (L3-hot: m fits in the 256 MiB L3 after K1a streamed it),
// recompute LN + gates, apply attention, write out NON-TEMPORAL (out's
// 134 MB of dirty lines must not evict m between K1a and K2).
// Loads batched 4-deep with a sched_barrier fence.
// ---------------------------------------------------------------------------
__global__ __launch_bounds__(256, 2) void msa_k2(
    const float* __restrict__ m,
    const float* __restrict__ lng, const float* __restrict__ lnb,
    const float* __restrict__ Wg, const float* __restrict__ bg,
    const float* __restrict__ Wo, const float* __restrict__ bo,
    const float* __restrict__ o_tab, float* __restrict__ out)
{
  const int tid = blockIdx.x * 256 + threadIdx.x;   // 524288 threads
  const int i = tid & (I_LEN - 1);

  // uniform derived vectors (SGPR-sourced weights)
  float sgv[8], tbv[8];
#pragma unroll
  for (int h = 0; h < 8; ++h) {
    float s = 0.f, tb = bg[h];
#pragma unroll
    for (int c = 0; c < 8; ++c) {
      s  = fmaf(lng[c], Wg[c * 8 + h], s);
      tb = fmaf(lnb[c], Wg[c * 8 + h], tb);
    }
    sgv[h] = s; tbv[h] = tb;
  }

  const float4* op = (const float4*)(o_tab + (size_t)i * 8);
  const float4 o1 = op[0], o2 = op[1];
  const float A[8] = {o1.x, o1.y, o1.z, o1.w, o2.x, o2.y, o2.z, o2.w};

#pragma unroll
  for (int g2 = 0; g2 < 2; ++g2) {
    float4 LO[4], HI[4];
#pragma unroll
    for (int r = 0; r < 4; ++r) {
      const size_t p = (size_t)tid + (size_t)(g2 * 4 + r) * 524288;
      const float4* mp = (const float4*)(m + p * 8);
      LO[r] = mp[0]; HI[r] = mp[1];
    }
    __builtin_amdgcn_sched_barrier(0);
#pragma unroll
    for (int r = 0; r < 4; ++r) {
      const size_t p = (size_t)tid + (size_t)(g2 * 4 + r) * 524288;
      float x[8] = {LO[r].x, LO[r].y, LO[r].z, LO[r].w,
                    HI[r].x, HI[r].y, HI[r].z, HI[r].w};
      float su = 0.f, s2 = 0.f;
#pragma unroll
      for (int c = 0; c < 8; ++c) { su += x[c]; s2 = fmaf(x[c], x[c], s2); }
      const float mu   = su * 0.125f;
      const float var  = s2 * 0.125f - mu * mu;
      const float rstd = rsqrtf(var + 1e-5f);
#pragma unroll
      for (int c = 0; c < 8; ++c) x[c] *= lng[c];
      float acc[8];
#pragma unroll
      for (int c = 0; c < 8; ++c) acc[c] = bo[c];
#pragma unroll
      for (int h = 0; h < 8; ++h) {
        float d = 0.f;
#pragma unroll
        for (int c = 0; c < 8; ++c) d = fmaf(x[c], Wg[c * 8 + h], d);
        const float gl = fmaf(rstd, fmaf(-mu, sgv[h], d), tbv[h]);
        const float gv = A[h] / (1.0f + __expf(-gl));
#pragma unroll
        for (int c = 0; c < 8; ++c) acc[c] = fmaf(gv, Wo[h * 8 + c], acc[c]);
      }
      f32x4* outp = (f32x4*)(out + p * 8);
      f32x4 r0 = {acc[0], acc[1], acc[2], acc[3]};
      f32x4 r1 = {acc[4], acc[5], acc[6], acc[7]};
      __builtin_nontemporal_store(r0, outp);
      __builtin_nontemporal_store(r1, outp + 1);
    }
  }
}

extern "C" void kernel_launch(void* const* d_in, const int* in_sizes, int n_in,
                              void* d_out, int out_size, void* d_ws, size_t ws_size,
                              hipStream_t stream) {
  const float* m    = (const float*)d_in[0];
  const float* mask = (const float*)d_in[1];
  const float* lng  = (const float*)d_in[2];
  const float* lnb  = (const float*)d_in[3];
  const float* Wq   = (const float*)d_in[4];
  const float* Wk   = (const float*)d_in[5];
  const float* Wv   = (const float*)d_in[6];
  const float* Wg   = (const float*)d_in[7];
  const float* bg   = (const float*)d_in[8];
  const float* Wo   = (const float*)d_in[9];
  const float* bo   = (const float*)d_in[10];
  float* out = (float*)d_out;

  // ws layout: o_tab 32KB @0 | qtab 32KB @64K | kvS 16.8MB @1M |
  //            qpart 6.3MB @32M | spart 8.4MB @48M
  char* ws = (char*)d_ws;
  float*        o_tab = (float*)ws;
  float*        qtab  = (float*)(ws + ((size_t)64 << 10));
  unsigned int* kvS   = (unsigned int*)(ws + ((size_t)1 << 20));
  float*        qpart = (float*)(ws + ((size_t)32 << 20));
  float*        spart = (float*)(ws + ((size_t)48 << 20));

  hipLaunchKernelGGL(msa_k1a, dim3(2048), dim3(256), 0, stream,
                     m, mask, lng, lnb, Wk, Wv, kvS, qpart);
  hipLaunchKernelGGL(msa_k1b, dim3(256), dim3(64), 0, stream,
                     lnb, Wq, qpart, qtab);
  hipLaunchKernelGGL(msa_k1c, dim3(2048), dim3(256), 0, stream,
                     kvS, qtab, spart);
  hipLaunchKernelGGL(msa_k1d, dim3(256), dim3(64), 0, stream,
                     spart, o_tab);
  hipLaunchKernelGGL(msa_k2, dim3(2048), dim3(256), 0, stream,
                     m, lng, lnb, Wg, bg, Wo, bo, o_tab, out);
}